// Round 10
// baseline (1293.665 us; speedup 1.0000x reference)
//
#include <hip/hip_runtime.h>
#include <hip/hip_bf16.h>
#include <hip/hip_cooperative_groups.h>

// GCN 7-layer forward on MI355X. R10:
//  - persistent cooperative kernel for all 13 layer phases (12 grid.sync()),
//    grid-stride everywhere: gather keeps one-node-per-wave (R6 lesson),
//    GEMMs keep MFMA (R8 lesson), NT=4 col-passes to cap VGPR.
//  - scan_fill2+slice_base merged (int4 slice walk, 4x fewer scratch ops).
//  - fallback: if cooperative launch fails, same phases as 13 dispatches.
//  Dispatches 18 -> 5.

namespace cg = cooperative_groups;

#define IN_F 128
#define NSLICE 60
#define SHB 13          // 8192 nodes/shard, 32 KB LDS
#define NSHARD 5        // ceil(40000/8192)

typedef __attribute__((ext_vector_type(8))) short short8v;   // 8 bf16
typedef __attribute__((ext_vector_type(4))) float f32x4;
typedef __attribute__((ext_vector_type(8))) _Float16 half8v; // 16 B

static __device__ __forceinline__ unsigned short f2bf(float x) {
    unsigned u = __builtin_bit_cast(unsigned, x);
    unsigned r = (u + 0x7FFFu + ((u >> 16) & 1u)) >> 16;   // rn-even
    return (unsigned short)r;
}
static __device__ __forceinline__ float bf2f(unsigned short h) {
    unsigned u = ((unsigned)h) << 16;
    return __builtin_bit_cast(float, u);
}

// ---------------- weight descriptors ----------------

struct WDesc { const float* w; unsigned short* th; unsigned short* tl; int K; int N; int cum; };
struct WPack { WDesc d[6]; int total; };

// ---------------- prep: LDS histogram (z=0,1) + weight split (z=2) ----------------

__global__ __launch_bounds__(256) void prep_kernel(const int* __restrict__ src,
                                                   const int* __restrict__ dst,
                                                   int* __restrict__ scratch,
                                                   WPack p, int E) {
    constexpr int SH = 1 << SHB;
    __shared__ int h[SH];
    const int t = threadIdx.x;
    const int b = blockIdx.x;
    const int s = blockIdx.y;
    const int z = blockIdx.z;
    if (z == 2) {
        int i = (b + NSLICE * s) * 256 + t;
        if (i >= p.total) return;
        int wi = 0;
#pragma unroll
        for (int q = 1; q < 6; ++q) if (i >= p.d[q].cum) wi = q;
        WDesc d = p.d[wi];
        int local = i - d.cum;
        int k = local / d.N, n = local - k * d.N;
        float v = d.w[local];
        unsigned short hh = f2bf(v);
        d.th[(size_t)n * d.K + k] = hh;
        d.tl[(size_t)n * d.K + k] = f2bf(v - bf2f(hh));
        return;
    }
    const int* idx = z ? dst : src;
    for (int i = t; i < SH; i += 256) h[i] = 0;
    __syncthreads();
    const int per = (E + NSLICE - 1) / NSLICE;
    const int lo = b * per;
    const int hiE = min(lo + per, E);
    const int base = s << SHB;
    for (int e = lo + t; e < hiE; e += 256) {
        unsigned a = (unsigned)(idx[e] - base);
        if (a < (unsigned)SH) atomicAdd(&h[a], 1);
    }
    __syncthreads();
    int* so = scratch + ((size_t)((z * NSHARD + s) * NSLICE + b) << SHB);
    for (int i = t; i < SH; i += 256) so[i] = h[i];
}

// ---------------- degree sums + norms + per-1024-node block sums ----------------

__global__ __launch_bounds__(256) void hist_reduce_blk(
    const int* __restrict__ scratch, int* __restrict__ in_deg,
    float* __restrict__ out_nrm, float* __restrict__ in_nrm,
    int* __restrict__ blockSums) {
    constexpr int SH = 1 << SHB;
    __shared__ int ws4[4];
    const int t = threadIdx.x;
    const int base = blockIdx.x * 1024 + t * 4;
    const int s = base >> SHB;
    const int i = base & (SH - 1);
    int od[4] = {0, 0, 0, 0}, id[4] = {0, 0, 0, 0};
    const int* po = scratch + (((size_t)s * NSLICE) << SHB) + i;
    const int* pi = scratch + (((size_t)(NSHARD + s) * NSLICE) << SHB) + i;
    for (int b = 0; b < NSLICE; ++b) {
        int4 o4 = *reinterpret_cast<const int4*>(po + ((size_t)b << SHB));
        int4 i4 = *reinterpret_cast<const int4*>(pi + ((size_t)b << SHB));
        od[0] += o4.x; od[1] += o4.y; od[2] += o4.z; od[3] += o4.w;
        id[0] += i4.x; id[1] += i4.y; id[2] += i4.z; id[3] += i4.w;
    }
    *reinterpret_cast<int4*>(&in_deg[base]) = make_int4(id[0], id[1], id[2], id[3]);
    float4 onf, inf;
    onf.x = od[0] > 0 ? rsqrtf((float)od[0]) : 0.f;
    onf.y = od[1] > 0 ? rsqrtf((float)od[1]) : 0.f;
    onf.z = od[2] > 0 ? rsqrtf((float)od[2]) : 0.f;
    onf.w = od[3] > 0 ? rsqrtf((float)od[3]) : 0.f;
    inf.x = id[0] > 0 ? rsqrtf((float)id[0]) : 0.f;
    inf.y = id[1] > 0 ? rsqrtf((float)id[1]) : 0.f;
    inf.z = id[2] > 0 ? rsqrtf((float)id[2]) : 0.f;
    inf.w = id[3] > 0 ? rsqrtf((float)id[3]) : 0.f;
    *reinterpret_cast<float4*>(&out_nrm[base]) = onf;
    *reinterpret_cast<float4*>(&in_nrm[base]) = inf;
    int ssum = id[0] + id[1] + id[2] + id[3];
#pragma unroll
    for (int off = 32; off > 0; off >>= 1) ssum += __shfl_down(ssum, off);
    if ((t & 63) == 0) ws4[t >> 6] = ssum;
    __syncthreads();
    if (t == 0) blockSums[blockIdx.x] = ws4[0] + ws4[1] + ws4[2] + ws4[3];
}

// ---------------- merged scan_fill + slice_base ----------------
// 40 blocks. Each block: top-scan offset (wave 0), per-node row_off, then
// int4 slice-base walk (nodes base..base+3 are in the same shard; N%4==0).

__global__ __launch_bounds__(256) void scanslice_kernel(const int* __restrict__ deg,
                                                        const int* __restrict__ blockSums,
                                                        int* __restrict__ row_off,
                                                        int* __restrict__ scratch,
                                                        int NBtop, int N, int E) {
    constexpr int SH = 1 << SHB;
    __shared__ int sOff;
    __shared__ int wtot[4];
    const int t = threadIdx.x;
    const int lane = t & 63;
    const int wid = t >> 6;
    if (wid == 0) {
        int v = (lane < NBtop && lane < blockIdx.x) ? blockSums[lane] : 0;
#pragma unroll
        for (int off = 32; off > 0; off >>= 1) v += __shfl_down(v, off);
        if (lane == 0) sOff = v;
    }
    const int base = blockIdx.x * 1024 + t * 4;
    int4 v = make_int4(0, 0, 0, 0);
    if (base + 3 < N) v = *reinterpret_cast<const int4*>(&deg[base]);
    else if (base < N) {
        v.x = deg[base];
        if (base + 1 < N) v.y = deg[base + 1];
        if (base + 2 < N) v.z = deg[base + 2];
    }
    const int s4 = v.x + v.y + v.z + v.w;
    int incl = s4;
#pragma unroll
    for (int off = 1; off < 64; off <<= 1) {
        int u = __shfl_up(incl, off);
        if (lane >= off) incl += u;
    }
    if (lane == 63) wtot[wid] = incl;
    __syncthreads();
    int pre = sOff + incl - s4;
    for (int i = 0; i < wid; ++i) pre += wtot[i];
    if (base + 3 < N) {   // N % 4 == 0 so full quads only (tail block has base >= N)
        int runs0 = pre;
        int runs1 = runs0 + v.x;
        int runs2 = runs1 + v.y;
        int runs3 = runs2 + v.z;
        *reinterpret_cast<int4*>(&row_off[base]) = make_int4(runs0, runs1, runs2, runs3);
        const int s = base >> SHB;
        const int i = base & (SH - 1);
        int4 run = make_int4(runs0, runs1, runs2, runs3);
        for (int b = 0; b < NSLICE; ++b) {
            size_t off = ((size_t)((NSHARD + s) * NSLICE + b) << SHB) + i;
            int4 c4 = *reinterpret_cast<const int4*>(&scratch[off]);
            *reinterpret_cast<int4*>(&scratch[off]) = run;
            run.x += c4.x; run.y += c4.y; run.z += c4.z; run.w += c4.w;
        }
    }
    if (blockIdx.x == 0 && t == 0) row_off[N] = E;
}

// place edges using LDS cursors seeded from slice bases; no global atomics
__global__ __launch_bounds__(256) void fill2_kernel(const int* __restrict__ src,
                                                    const int* __restrict__ dst,
                                                    const int* __restrict__ scratch,
                                                    int* __restrict__ csr, int E) {
    constexpr int SH = 1 << SHB;
    __shared__ int cur[SH];
    const int t = threadIdx.x;
    const int b = blockIdx.x;
    const int s = blockIdx.y;
    const int* base = scratch + ((size_t)((NSHARD + s) * NSLICE + b) << SHB);
    for (int i = t; i < SH; i += 256) cur[i] = base[i];
    __syncthreads();
    const int per = (E + NSLICE - 1) / NSLICE;
    const int lo = b * per;
    const int hiE = min(lo + per, E);
    const int nb = s << SHB;
    for (int e = lo + t; e < hiE; e += 256) {
        unsigned a = (unsigned)(dst[e] - nb);
        if (a < (unsigned)SH) {
            int pos = atomicAdd(&cur[a], 1);
            csr[pos] = src[e];
        }
    }
}

// ================= layer phase device functions (grid-stride) =================

// GEMM: 64-row x 64-col tile per block-iteration, NT=4 (acc 16 VGPR).
// F32IN: X fp32, scale by pre[] and split in regs. Else X fp16, split in regs.
// EPI: relu(acc*r+bias)*s. GEMV7 (NOUT=64): epilogue + dot W7 -> T7.
template<int K, int NOUT, bool EPI, bool GEMV7, bool F32IN>
__device__ __forceinline__ void gemm_phase(
    const void* Xv, const unsigned short* __restrict__ Bh,
    const unsigned short* __restrict__ Bl, const float* __restrict__ pre,
    const float* __restrict__ r_nrm, const float* __restrict__ s_nrm,
    const float* __restrict__ bias, const float* __restrict__ W7,
    _Float16* __restrict__ Y16, float* __restrict__ T7, int M, int G) {
    constexpr int CT = NOUT / 64;
    const int lane = threadIdx.x & 63;
    const int wv = threadIdx.x >> 6;
    const int c0 = lane & 15;
    const int kg = (lane >> 4) * 8;
    const int tiles = (M / 64) * CT;
    for (int tl = blockIdx.x; tl < tiles; tl += G) {
        const int rt = (CT == 1) ? tl : (tl >> 1);
        const int ct = (CT == 1) ? 0 : (tl & 1);
        const int r0 = rt * 64 + wv * 16;
        const int arow = r0 + c0;
        const int colB = ct * 64;
        const float sc = F32IN ? pre[arow] : 0.f;
        f32x4 acc[4];
#pragma unroll
        for (int n = 0; n < 4; ++n) acc[n] = (f32x4){0.f, 0.f, 0.f, 0.f};
        for (int kk = 0; kk < K; kk += 32) {
            short8v a_h, a_l;
            if (F32IN) {
                const float* ap = (const float*)Xv + (size_t)arow * K + kk + kg;
                float4 v0 = *reinterpret_cast<const float4*>(ap);
                float4 v1 = *reinterpret_cast<const float4*>(ap + 4);
                float a[8] = {v0.x, v0.y, v0.z, v0.w, v1.x, v1.y, v1.z, v1.w};
#pragma unroll
                for (int j = 0; j < 8; ++j) {
                    float f = a[j] * sc;
                    unsigned short hh = f2bf(f);
                    a_h[j] = (short)hh;
                    a_l[j] = (short)f2bf(f - bf2f(hh));
                }
            } else {
                half8v av = *reinterpret_cast<const half8v*>(
                    (const _Float16*)Xv + (size_t)arow * K + kk + kg);
#pragma unroll
                for (int j = 0; j < 8; ++j) {
                    float f = (float)av[j];
                    unsigned short hh = f2bf(f);
                    a_h[j] = (short)hh;
                    a_l[j] = (short)f2bf(f - bf2f(hh));
                }
            }
#pragma unroll
            for (int n = 0; n < 4; ++n) {
                int col = colB + n * 16 + c0;
                short8v b_h = *reinterpret_cast<const short8v*>(Bh + (size_t)col * K + kk + kg);
                short8v b_l = *reinterpret_cast<const short8v*>(Bl + (size_t)col * K + kk + kg);
                acc[n] = __builtin_amdgcn_mfma_f32_16x16x32_bf16(a_h, b_h, acc[n], 0, 0, 0);
                acc[n] = __builtin_amdgcn_mfma_f32_16x16x32_bf16(a_h, b_l, acc[n], 0, 0, 0);
                acc[n] = __builtin_amdgcn_mfma_f32_16x16x32_bf16(a_l, b_h, acc[n], 0, 0, 0);
            }
        }
        const int rr = r0 + (lane >> 4) * 4;
        if (GEMV7) {
            float w7c[4];
#pragma unroll
            for (int n = 0; n < 4; ++n) w7c[n] = W7[n * 16 + c0];
#pragma unroll
            for (int j = 0; j < 4; ++j) {
                const int row = rr + j;
                const float rn = r_nrm[row];
                const float sn = s_nrm[row];
                float pdot = 0.f;
#pragma unroll
                for (int n = 0; n < 4; ++n) {
                    float y = fmaf(acc[n][j], rn, bias[n * 16 + c0]);
                    y = fmaxf(y, 0.f) * sn;
                    pdot = fmaf(y, w7c[n], pdot);
                }
#pragma unroll
                for (int m = 8; m >= 1; m >>= 1) pdot += __shfl_xor(pdot, m);
                if (c0 == 0) T7[row] = pdot;
            }
        } else {
#pragma unroll
            for (int n = 0; n < 4; ++n) {
                const int col = colB + n * 16 + c0;
                const float bcol = EPI ? bias[col] : 0.f;
#pragma unroll
                for (int j = 0; j < 4; ++j) {
                    const int row = rr + j;
                    float y = acc[n][j];
                    if (EPI) {
                        y = fmaf(y, r_nrm[row], bcol);
                        y = fmaxf(y, 0.f);
                        y *= s_nrm[row];
                    }
                    Y16[(size_t)row * NOUT + col] = (_Float16)y;
                }
            }
        }
    }
}

// CSR aggregation: one node per wave, grid-stride; fp16 payload, fp32 accum.
template<int F, bool EPI>
__device__ __forceinline__ void agg_phase(
    const _Float16* __restrict__ X, const int* __restrict__ csr,
    const int* __restrict__ row_off, const float* __restrict__ r_nrm,
    const float* __restrict__ s_nrm, const float* __restrict__ bias,
    _Float16* __restrict__ Y16, int N, int G) {
    constexpr int LPE = F / 8;
    constexpr int EPW = 64 / LPE;
    const int lane = threadIdx.x & 63;
    const int gw = blockIdx.x * 4 + (threadIdx.x >> 6);
    const int nw = G * 4;
    const int g = lane / LPE;
    const int c = lane % LPE;
    for (int node = gw; node < N; node += nw) {
        const int lo = row_off[node];
        const int hi = row_off[node + 1];
        float acc[8], acc2[8];
#pragma unroll
        for (int j = 0; j < 8; ++j) { acc[j] = 0.f; acc2[j] = 0.f; }
        int e = lo + g;
        for (; e + EPW < hi; e += 2 * EPW) {
            int s0 = csr[e];
            int s1 = csr[e + EPW];
            half8v x0 = *reinterpret_cast<const half8v*>(&X[(size_t)s0 * F + c * 8]);
            half8v x1 = *reinterpret_cast<const half8v*>(&X[(size_t)s1 * F + c * 8]);
#pragma unroll
            for (int j = 0; j < 8; ++j) { acc[j] += (float)x0[j]; acc2[j] += (float)x1[j]; }
        }
        if (e < hi) {
            int s0 = csr[e];
            half8v x0 = *reinterpret_cast<const half8v*>(&X[(size_t)s0 * F + c * 8]);
#pragma unroll
            for (int j = 0; j < 8; ++j) acc[j] += (float)x0[j];
        }
#pragma unroll
        for (int j = 0; j < 8; ++j) acc[j] += acc2[j];
#pragma unroll
        for (int m = LPE; m < 64; m <<= 1) {
#pragma unroll
            for (int j = 0; j < 8; ++j) acc[j] += __shfl_xor(acc[j], m);
        }
        if (lane < LPE) {
            half8v o;
            if (EPI) {
                float rn = r_nrm[node];
                float sn = s_nrm[node];
#pragma unroll
                for (int j = 0; j < 8; ++j) {
                    float y = fmaf(acc[j], rn, bias[lane * 8 + j]);
                    o[j] = (_Float16)(fmaxf(y, 0.f) * sn);
                }
            } else {
#pragma unroll
                for (int j = 0; j < 8; ++j) o[j] = (_Float16)acc[j];
            }
            *reinterpret_cast<half8v*>(&Y16[(size_t)node * F + lane * 8]) = o;
        }
    }
}

__device__ __forceinline__ void agg1_phase(
    const float* __restrict__ T, const int* __restrict__ csr,
    const int* __restrict__ row_off, const float* __restrict__ r_nrm,
    const float* __restrict__ B7, float* __restrict__ Y, int N, int G) {
    const int g16 = (blockIdx.x * 256 + threadIdx.x) >> 4;
    const int l = threadIdx.x & 15;
    const int n16 = (G * 256) >> 4;
    const float b0 = B7[0];
    for (int node = g16; node < N; node += n16) {
        const int lo = row_off[node];
        const int hi = row_off[node + 1];
        float acc = 0.f;
        for (int e = lo + l; e < hi; e += 16) acc += T[csr[e]];
#pragma unroll
        for (int m = 8; m >= 1; m >>= 1) acc += __shfl_xor(acc, m);
        if (l == 0) Y[node] = fmaf(acc, r_nrm[node], b0);
    }
}

// ================= cooperative all-layers kernel =================

struct LParams {
    const float* in_feat;
    const int* csr; const int* row_off;
    const float* out_nrm; const float* in_nrm;
    const unsigned short* th0; const unsigned short* tl0;
    const unsigned short* th1; const unsigned short* tl1;
    const unsigned short* th2; const unsigned short* tl2;
    const unsigned short* th3; const unsigned short* tl3;
    const unsigned short* th4; const unsigned short* tl4;
    const unsigned short* th5; const unsigned short* tl5;
    const float* B1; const float* B2; const float* B3;
    const float* B4; const float* B5; const float* B6;
    const float* W7; const float* B7;
    _Float16* h0; _Float16* h1; float* t7; float* out;
    int N;
};

__global__ __launch_bounds__(256) void layers_kernel(LParams p) {
    cg::grid_group grid = cg::this_grid();
    const int G = gridDim.x;
    const int N = p.N;
#define GSYNC() do { __threadfence(); grid.sync(); } while (0)
    // L1: t1 = (x*s)@W1 -> h0 ; g1 = relu(agg(t1)*r+B1)*s -> h1
    gemm_phase<128, 64, false, false, true>(p.in_feat, p.th0, p.tl0, p.out_nrm,
        nullptr, nullptr, nullptr, nullptr, p.h0, nullptr, N, G);
    GSYNC();
    agg_phase<64, true>(p.h0, p.csr, p.row_off, p.in_nrm, p.out_nrm, p.B1, p.h1, N, G);
    GSYNC();
    // L2: t2 = agg(g1) -> h0 ; g2 = relu(t2@W2*r+B2)*s -> h1
    agg_phase<64, false>(p.h1, p.csr, p.row_off, nullptr, nullptr, nullptr, p.h0, N, G);
    GSYNC();
    gemm_phase<64, 128, true, false, false>(p.h0, p.th1, p.tl1, nullptr,
        p.in_nrm, p.out_nrm, p.B2, nullptr, p.h1, nullptr, N, G);
    GSYNC();
    // L3: t3 = agg(g2) -> h0 ; g3 -> h1
    agg_phase<128, false>(p.h1, p.csr, p.row_off, nullptr, nullptr, nullptr, p.h0, N, G);
    GSYNC();
    gemm_phase<128, 128, true, false, false>(p.h0, p.th2, p.tl2, nullptr,
        p.in_nrm, p.out_nrm, p.B3, nullptr, p.h1, nullptr, N, G);
    GSYNC();
    // L4: t4 = g3@W4 -> h0 ; g4 = relu(agg(t4)*r+B4)*s -> h1
    gemm_phase<128, 64, false, false, false>(p.h1, p.th3, p.tl3, nullptr,
        nullptr, nullptr, nullptr, nullptr, p.h0, nullptr, N, G);
    GSYNC();
    agg_phase<64, true>(p.h0, p.csr, p.row_off, p.in_nrm, p.out_nrm, p.B4, p.h1, N, G);
    GSYNC();
    // L5: t5 = agg(g4) -> h0 ; g5 -> h1
    agg_phase<64, false>(p.h1, p.csr, p.row_off, nullptr, nullptr, nullptr, p.h0, N, G);
    GSYNC();
    gemm_phase<64, 64, true, false, false>(p.h0, p.th4, p.tl4, nullptr,
        p.in_nrm, p.out_nrm, p.B5, nullptr, p.h1, nullptr, N, G);
    GSYNC();
    // L6: t6 = agg(g5) -> h0 ; gemm+epi+W7 dot -> t7
    agg_phase<64, false>(p.h1, p.csr, p.row_off, nullptr, nullptr, nullptr, p.h0, N, G);
    GSYNC();
    gemm_phase<64, 64, true, true, false>(p.h0, p.th5, p.tl5, nullptr,
        p.in_nrm, p.out_nrm, p.B6, p.W7, nullptr, p.t7, N, G);
    GSYNC();
    // out = agg(t7)*r + B7
    agg1_phase(p.t7, p.csr, p.row_off, p.in_nrm, p.B7, p.out, N, G);
#undef GSYNC
}

// ================= fallback wrapper kernels (R9 behavior) =================

template<int K, int NOUT, bool EPI, bool GEMV7, bool F32IN>
__global__ __launch_bounds__(256) void gemm_k(
    const void* X, const unsigned short* Bh, const unsigned short* Bl,
    const float* pre, const float* r_nrm, const float* s_nrm,
    const float* bias, const float* W7, _Float16* Y16, float* T7, int M) {
    gemm_phase<K, NOUT, EPI, GEMV7, F32IN>(X, Bh, Bl, pre, r_nrm, s_nrm,
                                           bias, W7, Y16, T7, M, gridDim.x);
}

template<int F, bool EPI>
__global__ __launch_bounds__(256) void agg_k(
    const _Float16* X, const int* csr, const int* row_off,
    const float* r_nrm, const float* s_nrm, const float* bias,
    _Float16* Y16, int N) {
    agg_phase<F, EPI>(X, csr, row_off, r_nrm, s_nrm, bias, Y16, N, gridDim.x);
}

__global__ __launch_bounds__(256) void agg1_k(
    const float* T, const int* csr, const int* row_off,
    const float* r_nrm, const float* B7, float* Y, int N) {
    agg1_phase(T, csr, row_off, r_nrm, B7, Y, N, gridDim.x);
}

// ================= host =================

extern "C" void kernel_launch(void* const* d_in, const int* in_sizes, int n_in,
                              void* d_out, int out_size, void* d_ws, size_t ws_size,
                              hipStream_t stream) {
    const float* in_feat = (const float*)d_in[0];
    const int* src = (const int*)d_in[1];
    const int* dst = (const int*)d_in[2];
    const float* W1 = (const float*)d_in[3];  const float* B1 = (const float*)d_in[4];
    const float* W2 = (const float*)d_in[5];  const float* B2 = (const float*)d_in[6];
    const float* W3 = (const float*)d_in[7];  const float* B3 = (const float*)d_in[8];
    const float* W4 = (const float*)d_in[9];  const float* B4 = (const float*)d_in[10];
    const float* W5 = (const float*)d_in[11]; const float* B5 = (const float*)d_in[12];
    const float* W6 = (const float*)d_in[13]; const float* B6 = (const float*)d_in[14];
    const float* W7 = (const float*)d_in[15]; const float* B7 = (const float*)d_in[16];

    const int N = in_sizes[0] / IN_F;        // 40000
    const int E = in_sizes[1];               // 640000
    const int N2 = NSHARD << SHB;            // 40960 (padded)
    float* out = (float*)d_out;

    // workspace layout (256B aligned)
    char* w = (char*)d_ws;
    auto alloc = [&](size_t bytes) { char* p = w; w += (bytes + 255) & ~(size_t)255; return p; };
    int* csr      = (int*)alloc((size_t)E * 4);
    int* row_off  = (int*)alloc((size_t)(N + 1) * 4);
    int* in_deg   = (int*)alloc((size_t)N2 * 4);
    int* blockSums= (int*)alloc(64 * 4);
    float* out_nrm= (float*)alloc((size_t)N2 * 4);
    float* in_nrm = (float*)alloc((size_t)N2 * 4);
    float* t7     = (float*)alloc((size_t)N * 4);
    const int dims[8] = {128, 64, 128, 128, 64, 64, 64, 1};
    unsigned short* wth[6]; unsigned short* wtl[6];
    for (int i = 0; i < 6; ++i) {
        size_t kn = (size_t)dims[i] * dims[i + 1];
        wth[i] = (unsigned short*)alloc(kn * 2);
        wtl[i] = (unsigned short*)alloc(kn * 2);
    }
    _Float16* h0 = (_Float16*)alloc((size_t)N * 128 * 2);   // 10.24 MB
    _Float16* h1 = (_Float16*)alloc((size_t)N * 128 * 2);
    // hist scratch (19.66 MB) aliases h0+h1 (20.48 MB); consumed by fill2.
    int* scratch = (int*)h0;
    (void)ws_size; (void)n_in; (void)out_size;

    const int TB = 256;
    const int NB = N2 / 1024;   // 40

    WPack wp;
    const float* Ws[6] = {W1, W2, W3, W4, W5, W6};
    int cum = 0;
    for (int i = 0; i < 6; ++i) {
        wp.d[i] = {Ws[i], wth[i], wtl[i], dims[i], dims[i + 1], cum};
        cum += dims[i] * dims[i + 1];
    }
    wp.total = cum;   // 49152

    // CSR + norms (atomic-free) + weight split
    prep_kernel<<<dim3(NSLICE, NSHARD, 3), TB, 0, stream>>>(src, dst, scratch, wp, E);
    hist_reduce_blk<<<NB, TB, 0, stream>>>(scratch, in_deg, out_nrm, in_nrm, blockSums);
    scanslice_kernel<<<NB, TB, 0, stream>>>(in_deg, blockSums, row_off, scratch, NB, N, E);
    fill2_kernel<<<dim3(NSLICE, NSHARD), TB, 0, stream>>>(src, dst, scratch, csr, E);

    // ---- layers: one cooperative dispatch (fallback: 13 dispatches) ----
    LParams lp;
    lp.in_feat = in_feat; lp.csr = csr; lp.row_off = row_off;
    lp.out_nrm = out_nrm; lp.in_nrm = in_nrm;
    lp.th0 = wth[0]; lp.tl0 = wtl[0]; lp.th1 = wth[1]; lp.tl1 = wtl[1];
    lp.th2 = wth[2]; lp.tl2 = wtl[2]; lp.th3 = wth[3]; lp.tl3 = wtl[3];
    lp.th4 = wth[4]; lp.tl4 = wtl[4]; lp.th5 = wth[5]; lp.tl5 = wtl[5];
    lp.B1 = B1; lp.B2 = B2; lp.B3 = B3; lp.B4 = B4; lp.B5 = B5; lp.B6 = B6;
    lp.W7 = W7; lp.B7 = B7;
    lp.h0 = h0; lp.h1 = h1; lp.t7 = t7; lp.out = out;
    lp.N = N;

    int nbPerCU = 0;
    hipError_t oe = hipOccupancyMaxActiveBlocksPerMultiprocessor(&nbPerCU, layers_kernel, TB, 0);
    int G = (oe == hipSuccess && nbPerCU > 0) ? nbPerCU * 256 : 0;
    if (G > 10000) G = 10000;

    hipError_t le = hipErrorUnknown;
    if (G > 0) {
        void* args[] = {&lp};
        le = hipLaunchCooperativeKernel((void*)layers_kernel, dim3(G), dim3(TB), args, 0, stream);
    }
    if (le != hipSuccess) {
        // fallback: separate dispatches (R9 structure)
        const int gridN4 = (N + 3) / 4;
        const int MB = N / 64;          // 625
        gemm_k<128, 64, false, false, true><<<MB, TB, 0, stream>>>(
            in_feat, wth[0], wtl[0], out_nrm, nullptr, nullptr, nullptr, nullptr, h0, nullptr, N);
        agg_k<64, true><<<gridN4, TB, 0, stream>>>(h0, csr, row_off, in_nrm, out_nrm, B1, h1, N);
        agg_k<64, false><<<gridN4, TB, 0, stream>>>(h1, csr, row_off, nullptr, nullptr, nullptr, h0, N);
        gemm_k<64, 128, true, false, false><<<MB * 2, TB, 0, stream>>>(
            h0, wth[1], wtl[1], nullptr, in_nrm, out_nrm, B2, nullptr, h1, nullptr, N);
        agg_k<128, false><<<gridN4, TB, 0, stream>>>(h1, csr, row_off, nullptr, nullptr, nullptr, h0, N);
        gemm_k<128, 128, true, false, false><<<MB * 2, TB, 0, stream>>>(
            h0, wth[2], wtl[2], nullptr, in_nrm, out_nrm, B3, nullptr, h1, nullptr, N);
        gemm_k<128, 64, false, false, false><<<MB, TB, 0, stream>>>(
            h1, wth[3], wtl[3], nullptr, nullptr, nullptr, nullptr, nullptr, h0, nullptr, N);
        agg_k<64, true><<<gridN4, TB, 0, stream>>>(h0, csr, row_off, in_nrm, out_nrm, B4, h1, N);
        agg_k<64, false><<<gridN4, TB, 0, stream>>>(h1, csr, row_off, nullptr, nullptr, nullptr, h0, N);
        gemm_k<64, 64, true, false, false><<<MB, TB, 0, stream>>>(
            h0, wth[4], wtl[4], nullptr, in_nrm, out_nrm, B5, nullptr, h1, nullptr, N);
        agg_k<64, false><<<gridN4, TB, 0, stream>>>(h1, csr, row_off, nullptr, nullptr, nullptr, h0, N);
        gemm_k<64, 64, true, true, false><<<MB, TB, 0, stream>>>(
            h0, wth[5], wtl[5], nullptr, in_nrm, out_nrm, B6, W7, nullptr, t7, N);
        agg1_k<<<(N + 15) / 16, TB, 0, stream>>>(t7, csr, row_off, in_nrm, B7, out, N);
    }
}

// Round 11
// 298.465 us; speedup vs baseline: 4.3344x; 4.3344x over previous
//
#include <hip/hip_runtime.h>
#include <hip/hip_bf16.h>

// GCN 7-layer forward on MI355X. R11:
//  - REVERT R10 cooperative kernel (grid.sync() on 8-XCD MI355X costs ~100us
//    each through device-scope memory; 12 syncs = +1.2ms. Dispatch boundaries
//    are CHEAP. Lesson logged.) Back to R9 structure (294.5us best).
//  - agg_h16: 4-deep edge unroll (32 outstanding 16B loads/wave for F=64) —
//    discriminates latency-bound vs BW-bound gather.

#define IN_F 128
#define NSLICE 60
#define SHB 13          // 8192 nodes/shard, 32 KB LDS
#define NSHARD 5        // ceil(40000/8192)

typedef __attribute__((ext_vector_type(8))) short short8v;   // 8 bf16
typedef __attribute__((ext_vector_type(4))) float f32x4;
typedef __attribute__((ext_vector_type(8))) _Float16 half8v; // 16 B

static __device__ __forceinline__ unsigned short f2bf(float x) {
    unsigned u = __builtin_bit_cast(unsigned, x);
    unsigned r = (u + 0x7FFFu + ((u >> 16) & 1u)) >> 16;   // rn-even
    return (unsigned short)r;
}
static __device__ __forceinline__ float bf2f(unsigned short h) {
    unsigned u = ((unsigned)h) << 16;
    return __builtin_bit_cast(float, u);
}

// ---------------- weight descriptors ----------------

struct WDesc { const float* w; unsigned short* th; unsigned short* tl; int K; int N; int cum; };
struct WPack { WDesc d[6]; int total; };

// ---------------- prep: LDS histogram (z=0,1) + weight split (z=2) ----------------

__global__ __launch_bounds__(256) void prep_kernel(const int* __restrict__ src,
                                                   const int* __restrict__ dst,
                                                   int* __restrict__ scratch,
                                                   WPack p, int E) {
    constexpr int SH = 1 << SHB;
    __shared__ int h[SH];
    const int t = threadIdx.x;
    const int b = blockIdx.x;
    const int s = blockIdx.y;
    const int z = blockIdx.z;
    if (z == 2) {
        int i = (b + NSLICE * s) * 256 + t;
        if (i >= p.total) return;
        int wi = 0;
#pragma unroll
        for (int q = 1; q < 6; ++q) if (i >= p.d[q].cum) wi = q;
        WDesc d = p.d[wi];
        int local = i - d.cum;
        int k = local / d.N, n = local - k * d.N;
        float v = d.w[local];
        unsigned short hh = f2bf(v);
        d.th[(size_t)n * d.K + k] = hh;
        d.tl[(size_t)n * d.K + k] = f2bf(v - bf2f(hh));
        return;
    }
    const int* idx = z ? dst : src;
    for (int i = t; i < SH; i += 256) h[i] = 0;
    __syncthreads();
    const int per = (E + NSLICE - 1) / NSLICE;
    const int lo = b * per;
    const int hiE = min(lo + per, E);
    const int base = s << SHB;
    for (int e = lo + t; e < hiE; e += 256) {
        unsigned a = (unsigned)(idx[e] - base);
        if (a < (unsigned)SH) atomicAdd(&h[a], 1);
    }
    __syncthreads();
    int* so = scratch + ((size_t)((z * NSHARD + s) * NSLICE + b) << SHB);
    for (int i = t; i < SH; i += 256) so[i] = h[i];
}

// ---------------- degree sums + norms + per-1024-node block sums ----------------

__global__ __launch_bounds__(256) void hist_reduce_blk(
    const int* __restrict__ scratch, int* __restrict__ in_deg,
    float* __restrict__ out_nrm, float* __restrict__ in_nrm,
    int* __restrict__ blockSums) {
    constexpr int SH = 1 << SHB;
    __shared__ int ws4[4];
    const int t = threadIdx.x;
    const int base = blockIdx.x * 1024 + t * 4;
    const int s = base >> SHB;
    const int i = base & (SH - 1);
    int od[4] = {0, 0, 0, 0}, id[4] = {0, 0, 0, 0};
    const int* po = scratch + (((size_t)s * NSLICE) << SHB) + i;
    const int* pi = scratch + (((size_t)(NSHARD + s) * NSLICE) << SHB) + i;
    for (int b = 0; b < NSLICE; ++b) {
        int4 o4 = *reinterpret_cast<const int4*>(po + ((size_t)b << SHB));
        int4 i4 = *reinterpret_cast<const int4*>(pi + ((size_t)b << SHB));
        od[0] += o4.x; od[1] += o4.y; od[2] += o4.z; od[3] += o4.w;
        id[0] += i4.x; id[1] += i4.y; id[2] += i4.z; id[3] += i4.w;
    }
    *reinterpret_cast<int4*>(&in_deg[base]) = make_int4(id[0], id[1], id[2], id[3]);
    float4 onf, inf;
    onf.x = od[0] > 0 ? rsqrtf((float)od[0]) : 0.f;
    onf.y = od[1] > 0 ? rsqrtf((float)od[1]) : 0.f;
    onf.z = od[2] > 0 ? rsqrtf((float)od[2]) : 0.f;
    onf.w = od[3] > 0 ? rsqrtf((float)od[3]) : 0.f;
    inf.x = id[0] > 0 ? rsqrtf((float)id[0]) : 0.f;
    inf.y = id[1] > 0 ? rsqrtf((float)id[1]) : 0.f;
    inf.z = id[2] > 0 ? rsqrtf((float)id[2]) : 0.f;
    inf.w = id[3] > 0 ? rsqrtf((float)id[3]) : 0.f;
    *reinterpret_cast<float4*>(&out_nrm[base]) = onf;
    *reinterpret_cast<float4*>(&in_nrm[base]) = inf;
    int ssum = id[0] + id[1] + id[2] + id[3];
#pragma unroll
    for (int off = 32; off > 0; off >>= 1) ssum += __shfl_down(ssum, off);
    if ((t & 63) == 0) ws4[t >> 6] = ssum;
    __syncthreads();
    if (t == 0) blockSums[blockIdx.x] = ws4[0] + ws4[1] + ws4[2] + ws4[3];
}

// ---------------- merged scan_fill + slice_base ----------------

__global__ __launch_bounds__(256) void scanslice_kernel(const int* __restrict__ deg,
                                                        const int* __restrict__ blockSums,
                                                        int* __restrict__ row_off,
                                                        int* __restrict__ scratch,
                                                        int NBtop, int N, int E) {
    constexpr int SH = 1 << SHB;
    __shared__ int sOff;
    __shared__ int wtot[4];
    const int t = threadIdx.x;
    const int lane = t & 63;
    const int wid = t >> 6;
    if (wid == 0) {
        int v = (lane < NBtop && lane < blockIdx.x) ? blockSums[lane] : 0;
#pragma unroll
        for (int off = 32; off > 0; off >>= 1) v += __shfl_down(v, off);
        if (lane == 0) sOff = v;
    }
    const int base = blockIdx.x * 1024 + t * 4;
    int4 v = make_int4(0, 0, 0, 0);
    if (base + 3 < N) v = *reinterpret_cast<const int4*>(&deg[base]);
    else if (base < N) {
        v.x = deg[base];
        if (base + 1 < N) v.y = deg[base + 1];
        if (base + 2 < N) v.z = deg[base + 2];
    }
    const int s4 = v.x + v.y + v.z + v.w;
    int incl = s4;
#pragma unroll
    for (int off = 1; off < 64; off <<= 1) {
        int u = __shfl_up(incl, off);
        if (lane >= off) incl += u;
    }
    if (lane == 63) wtot[wid] = incl;
    __syncthreads();
    int pre = sOff + incl - s4;
    for (int i = 0; i < wid; ++i) pre += wtot[i];
    if (base + 3 < N) {   // N % 4 == 0: full quads only
        int runs0 = pre;
        int runs1 = runs0 + v.x;
        int runs2 = runs1 + v.y;
        int runs3 = runs2 + v.z;
        *reinterpret_cast<int4*>(&row_off[base]) = make_int4(runs0, runs1, runs2, runs3);
        const int s = base >> SHB;
        const int i = base & (SH - 1);
        int4 run = make_int4(runs0, runs1, runs2, runs3);
        for (int b = 0; b < NSLICE; ++b) {
            size_t off = ((size_t)((NSHARD + s) * NSLICE + b) << SHB) + i;
            int4 c4 = *reinterpret_cast<const int4*>(&scratch[off]);
            *reinterpret_cast<int4*>(&scratch[off]) = run;
            run.x += c4.x; run.y += c4.y; run.z += c4.z; run.w += c4.w;
        }
    }
    if (blockIdx.x == 0 && t == 0) row_off[N] = E;
}

// place edges using LDS cursors seeded from slice bases; no global atomics
__global__ __launch_bounds__(256) void fill2_kernel(const int* __restrict__ src,
                                                    const int* __restrict__ dst,
                                                    const int* __restrict__ scratch,
                                                    int* __restrict__ csr, int E) {
    constexpr int SH = 1 << SHB;
    __shared__ int cur[SH];
    const int t = threadIdx.x;
    const int b = blockIdx.x;
    const int s = blockIdx.y;
    const int* base = scratch + ((size_t)((NSHARD + s) * NSLICE + b) << SHB);
    for (int i = t; i < SH; i += 256) cur[i] = base[i];
    __syncthreads();
    const int per = (E + NSLICE - 1) / NSLICE;
    const int lo = b * per;
    const int hiE = min(lo + per, E);
    const int nb = s << SHB;
    for (int e = lo + t; e < hiE; e += 256) {
        unsigned a = (unsigned)(dst[e] - nb);
        if (a < (unsigned)SH) {
            int pos = atomicAdd(&cur[a], 1);
            csr[pos] = src[e];
        }
    }
}

// ---------------- L1 GEMM: fp32 input, scale+split in registers ----------------

template<int K, int NOUT>
__global__ __launch_bounds__(256) void gemm_mfma_f32(
    const float* __restrict__ X,
    const unsigned short* __restrict__ Bh, const unsigned short* __restrict__ Bl,
    const float* __restrict__ pre, _Float16* __restrict__ Y16, int M) {
    constexpr int NT = NOUT / 16;
    const int lane = threadIdx.x & 63;
    const int wv = threadIdx.x >> 6;
    const int r0 = blockIdx.x * 64 + wv * 16;
    const int arow = r0 + (lane & 15);
    const int kg = (lane >> 4) * 8;
    const float sc = pre[arow];

    f32x4 acc[NT];
#pragma unroll
    for (int n = 0; n < NT; ++n) acc[n] = (f32x4){0.f, 0.f, 0.f, 0.f};

    for (int kk = 0; kk < K; kk += 32) {
        const float* ap = &X[(size_t)arow * K + kk + kg];
        float4 v0 = *reinterpret_cast<const float4*>(ap);
        float4 v1 = *reinterpret_cast<const float4*>(ap + 4);
        float a[8] = {v0.x, v0.y, v0.z, v0.w, v1.x, v1.y, v1.z, v1.w};
        short8v a_h, a_l;
#pragma unroll
        for (int j = 0; j < 8; ++j) {
            float f = a[j] * sc;
            unsigned short hh = f2bf(f);
            a_h[j] = (short)hh;
            a_l[j] = (short)f2bf(f - bf2f(hh));
        }
#pragma unroll
        for (int n = 0; n < NT; ++n) {
            int col = n * 16 + (lane & 15);
            short8v b_h = *reinterpret_cast<const short8v*>(Bh + (size_t)col * K + kk + kg);
            short8v b_l = *reinterpret_cast<const short8v*>(Bl + (size_t)col * K + kk + kg);
            acc[n] = __builtin_amdgcn_mfma_f32_16x16x32_bf16(a_h, b_h, acc[n], 0, 0, 0);
            acc[n] = __builtin_amdgcn_mfma_f32_16x16x32_bf16(a_h, b_l, acc[n], 0, 0, 0);
            acc[n] = __builtin_amdgcn_mfma_f32_16x16x32_bf16(a_l, b_h, acc[n], 0, 0, 0);
        }
    }
    const int c0 = lane & 15;
    const int rr = r0 + (lane >> 4) * 4;
#pragma unroll
    for (int n = 0; n < NT; ++n) {
        const int col = n * 16 + c0;
#pragma unroll
        for (int j = 0; j < 4; ++j)
            Y16[(size_t)(rr + j) * NOUT + col] = (_Float16)acc[n][j];
    }
}

// ---------------- GEMM: fp16 A, split to bf16 hi/lo in registers ----------------

template<int K, int NOUT, bool EPI, bool GEMV7>
__global__ __launch_bounds__(256) void gemm_h16(
    const _Float16* __restrict__ X,
    const unsigned short* __restrict__ Bh, const unsigned short* __restrict__ Bl,
    const float* __restrict__ r_nrm, const float* __restrict__ s_nrm,
    const float* __restrict__ bias, const float* __restrict__ W7,
    _Float16* __restrict__ Y16, float* __restrict__ T7, int M) {
    constexpr int NT = NOUT / 16;
    const int lane = threadIdx.x & 63;
    const int wv = threadIdx.x >> 6;
    const int r0 = blockIdx.x * 64 + wv * 16;
    const int arow = r0 + (lane & 15);
    const int kg = (lane >> 4) * 8;

    f32x4 acc[NT];
#pragma unroll
    for (int n = 0; n < NT; ++n) acc[n] = (f32x4){0.f, 0.f, 0.f, 0.f};

    for (int kk = 0; kk < K; kk += 32) {
        half8v av = *reinterpret_cast<const half8v*>(&X[(size_t)arow * K + kk + kg]);
        short8v a_h, a_l;
#pragma unroll
        for (int j = 0; j < 8; ++j) {
            float f = (float)av[j];
            unsigned short hh = f2bf(f);
            a_h[j] = (short)hh;
            a_l[j] = (short)f2bf(f - bf2f(hh));
        }
#pragma unroll
        for (int n = 0; n < NT; ++n) {
            int col = n * 16 + (lane & 15);
            short8v b_h = *reinterpret_cast<const short8v*>(Bh + (size_t)col * K + kk + kg);
            short8v b_l = *reinterpret_cast<const short8v*>(Bl + (size_t)col * K + kk + kg);
            acc[n] = __builtin_amdgcn_mfma_f32_16x16x32_bf16(a_h, b_h, acc[n], 0, 0, 0);
            acc[n] = __builtin_amdgcn_mfma_f32_16x16x32_bf16(a_h, b_l, acc[n], 0, 0, 0);
            acc[n] = __builtin_amdgcn_mfma_f32_16x16x32_bf16(a_l, b_h, acc[n], 0, 0, 0);
        }
    }
    const int c0 = lane & 15;
    const int rr = r0 + (lane >> 4) * 4;
    if (GEMV7) {
        float w7c[NT];
#pragma unroll
        for (int n = 0; n < NT; ++n) w7c[n] = W7[n * 16 + c0];
#pragma unroll
        for (int j = 0; j < 4; ++j) {
            const int row = rr + j;
            const float rn = r_nrm[row];
            const float sn = s_nrm[row];
            float p = 0.f;
#pragma unroll
            for (int n = 0; n < NT; ++n) {
                float y = fmaf(acc[n][j], rn, bias[n * 16 + c0]);
                y = fmaxf(y, 0.f) * sn;
                p = fmaf(y, w7c[n], p);
            }
#pragma unroll
            for (int m = 8; m >= 1; m >>= 1) p += __shfl_xor(p, m);
            if (c0 == 0) T7[row] = p;
        }
    } else {
#pragma unroll
        for (int n = 0; n < NT; ++n) {
            const int col = n * 16 + c0;
            const float bcol = EPI ? bias[col] : 0.f;
#pragma unroll
            for (int j = 0; j < 4; ++j) {
                const int row = rr + j;
                float y = acc[n][j];
                if (EPI) {
                    y = fmaf(y, r_nrm[row], bcol);
                    y = fmaxf(y, 0.f);
                    y *= s_nrm[row];
                }
                Y16[(size_t)row * NOUT + col] = (_Float16)y;
            }
        }
    }
}

// ---------------- fp16 CSR aggregation, 4-deep unroll, fp16 out ----------------
// F=64: 8 lanes/row, 8 edges/step, 32 edges (32 x 16B loads) in flight.
// F=128: 16 lanes/row, 4 edges/step, 16 in flight.

template<int F, bool EPI>
__global__ __launch_bounds__(256) void agg_h16(
    const _Float16* __restrict__ X, const int* __restrict__ csr,
    const int* __restrict__ row_off, const float* __restrict__ r_nrm,
    const float* __restrict__ s_nrm, const float* __restrict__ bias,
    _Float16* __restrict__ Y16, int N) {
    constexpr int LPE = F / 8;
    constexpr int EPW = 64 / LPE;
    const int lane = threadIdx.x & 63;
    const int node = blockIdx.x * (blockDim.x >> 6) + (threadIdx.x >> 6);
    if (node >= N) return;
    const int g = lane / LPE;
    const int c = lane % LPE;
    const int lo = row_off[node];
    const int hi = row_off[node + 1];
    float acc[8], acc2[8];
#pragma unroll
    for (int j = 0; j < 8; ++j) { acc[j] = 0.f; acc2[j] = 0.f; }
    int e = lo + g;
    for (; e + 3 * EPW < hi; e += 4 * EPW) {
        int s0 = csr[e];
        int s1 = csr[e + EPW];
        int s2 = csr[e + 2 * EPW];
        int s3 = csr[e + 3 * EPW];
        half8v x0 = *reinterpret_cast<const half8v*>(&X[(size_t)s0 * F + c * 8]);
        half8v x1 = *reinterpret_cast<const half8v*>(&X[(size_t)s1 * F + c * 8]);
        half8v x2 = *reinterpret_cast<const half8v*>(&X[(size_t)s2 * F + c * 8]);
        half8v x3 = *reinterpret_cast<const half8v*>(&X[(size_t)s3 * F + c * 8]);
#pragma unroll
        for (int j = 0; j < 8; ++j) {
            acc[j] += (float)x0[j] + (float)x2[j];
            acc2[j] += (float)x1[j] + (float)x3[j];
        }
    }
    for (; e < hi; e += EPW) {
        int s0 = csr[e];
        half8v x0 = *reinterpret_cast<const half8v*>(&X[(size_t)s0 * F + c * 8]);
#pragma unroll
        for (int j = 0; j < 8; ++j) acc[j] += (float)x0[j];
    }
#pragma unroll
    for (int j = 0; j < 8; ++j) acc[j] += acc2[j];
#pragma unroll
    for (int m = LPE; m < 64; m <<= 1) {
#pragma unroll
        for (int j = 0; j < 8; ++j) acc[j] += __shfl_xor(acc[j], m);
    }
    if (lane < LPE) {
        half8v o;
        if (EPI) {
            float rn = r_nrm[node];
            float sn = s_nrm[node];
#pragma unroll
            for (int j = 0; j < 8; ++j) {
                float y = fmaf(acc[j], rn, bias[lane * 8 + j]);
                o[j] = (_Float16)(fmaxf(y, 0.f) * sn);
            }
        } else {
#pragma unroll
            for (int j = 0; j < 8; ++j) o[j] = (_Float16)acc[j];
        }
        *reinterpret_cast<half8v*>(&Y16[(size_t)node * F + lane * 8]) = o;
    }
}

// ---------------- final scalar aggregation ----------------

__global__ __launch_bounds__(256) void agg1_kernel(const float* __restrict__ T,
                                                   const int* __restrict__ csr,
                                                   const int* __restrict__ row_off,
                                                   const float* __restrict__ r_nrm,
                                                   const float* __restrict__ bias,
                                                   float* __restrict__ Y, int N) {
    const int node = blockIdx.x * 16 + (threadIdx.x >> 4);
    const int l = threadIdx.x & 15;
    if (node >= N) return;
    const int lo = row_off[node];
    const int hi = row_off[node + 1];
    float acc = 0.f;
    for (int e = lo + l; e < hi; e += 16) acc += T[csr[e]];
#pragma unroll
    for (int m = 8; m >= 1; m >>= 1) acc += __shfl_xor(acc, m);
    if (l == 0) Y[node] = fmaf(acc, r_nrm[node], bias[0]);
}

// ---------------- host ----------------

extern "C" void kernel_launch(void* const* d_in, const int* in_sizes, int n_in,
                              void* d_out, int out_size, void* d_ws, size_t ws_size,
                              hipStream_t stream) {
    const float* in_feat = (const float*)d_in[0];
    const int* src = (const int*)d_in[1];
    const int* dst = (const int*)d_in[2];
    const float* W1 = (const float*)d_in[3];  const float* B1 = (const float*)d_in[4];
    const float* W2 = (const float*)d_in[5];  const float* B2 = (const float*)d_in[6];
    const float* W3 = (const float*)d_in[7];  const float* B3 = (const float*)d_in[8];
    const float* W4 = (const float*)d_in[9];  const float* B4 = (const float*)d_in[10];
    const float* W5 = (const float*)d_in[11]; const float* B5 = (const float*)d_in[12];
    const float* W6 = (const float*)d_in[13]; const float* B6 = (const float*)d_in[14];
    const float* W7 = (const float*)d_in[15]; const float* B7 = (const float*)d_in[16];

    const int N = in_sizes[0] / IN_F;        // 40000
    const int E = in_sizes[1];               // 640000
    const int N2 = NSHARD << SHB;            // 40960 (padded)
    float* out = (float*)d_out;

    // workspace layout (256B aligned)
    char* w = (char*)d_ws;
    auto alloc = [&](size_t bytes) { char* p = w; w += (bytes + 255) & ~(size_t)255; return p; };
    int* csr      = (int*)alloc((size_t)E * 4);
    int* row_off  = (int*)alloc((size_t)(N + 1) * 4);
    int* in_deg   = (int*)alloc((size_t)N2 * 4);
    int* blockSums= (int*)alloc(64 * 4);
    float* out_nrm= (float*)alloc((size_t)N2 * 4);
    float* in_nrm = (float*)alloc((size_t)N2 * 4);
    float* t7     = (float*)alloc((size_t)N * 4);
    const int dims[8] = {128, 64, 128, 128, 64, 64, 64, 1};
    unsigned short* wth[6]; unsigned short* wtl[6];
    for (int i = 0; i < 6; ++i) {
        size_t kn = (size_t)dims[i] * dims[i + 1];
        wth[i] = (unsigned short*)alloc(kn * 2);
        wtl[i] = (unsigned short*)alloc(kn * 2);
    }
    _Float16* h0 = (_Float16*)alloc((size_t)N * 128 * 2);   // 10.24 MB
    _Float16* h1 = (_Float16*)alloc((size_t)N * 128 * 2);
    // hist scratch (19.66 MB) aliases h0+h1 (20.48 MB); consumed by fill2.
    int* scratch = (int*)h0;
    (void)ws_size; (void)n_in; (void)out_size;

    const int TB = 256;
    const int NB = N2 / 1024;   // 40

    WPack wp;
    const float* Ws[6] = {W1, W2, W3, W4, W5, W6};
    int cum = 0;
    for (int i = 0; i < 6; ++i) {
        wp.d[i] = {Ws[i], wth[i], wtl[i], dims[i], dims[i + 1], cum};
        cum += dims[i] * dims[i + 1];
    }
    wp.total = cum;   // 49152

    // CSR + norms (atomic-free) + weight split
    prep_kernel<<<dim3(NSLICE, NSHARD, 3), TB, 0, stream>>>(src, dst, scratch, wp, E);
    hist_reduce_blk<<<NB, TB, 0, stream>>>(scratch, in_deg, out_nrm, in_nrm, blockSums);
    scanslice_kernel<<<NB, TB, 0, stream>>>(in_deg, blockSums, row_off, scratch, NB, N, E);
    fill2_kernel<<<dim3(NSLICE, NSHARD), TB, 0, stream>>>(src, dst, scratch, csr, E);

    const int gridN4 = (N + 3) / 4;   // one node per wave
    const int MB = (N + 63) / 64;     // 625

    // L1: 128->64 mult-first. h0 = t1 = (x*s)@W1 ; h1 = g1 = relu(agg(t1)*r+B1)*s
    gemm_mfma_f32<128, 64><<<MB, TB, 0, stream>>>(in_feat, wth[0], wtl[0], out_nrm, h0, N);
    agg_h16<64, true><<<gridN4, TB, 0, stream>>>(h0, csr, row_off, in_nrm, out_nrm, B1, h1, N);

    // L2: 64->128 agg-first. h0 = t2 = agg(g1) ; h1 = g2 = relu(t2@W2*r+B2)*s
    agg_h16<64, false><<<gridN4, TB, 0, stream>>>(h1, csr, row_off, nullptr, nullptr, nullptr, h0, N);
    gemm_h16<64, 128, true, false><<<MB, TB, 0, stream>>>(
        h0, wth[1], wtl[1], in_nrm, out_nrm, B2, nullptr, h1, nullptr, N);

    // L3: 128->128 agg-first. h0 = t3 = agg(g2) ; h1 = g3
    agg_h16<128, false><<<gridN4, TB, 0, stream>>>(h1, csr, row_off, nullptr, nullptr, nullptr, h0, N);
    gemm_h16<128, 128, true, false><<<MB, TB, 0, stream>>>(
        h0, wth[2], wtl[2], in_nrm, out_nrm, B3, nullptr, h1, nullptr, N);

    // L4: 128->64 mult-first. h0 = t4 = g3@W4 ; h1 = g4 = relu(agg(t4)*r+B4)*s
    gemm_h16<128, 64, false, false><<<MB, TB, 0, stream>>>(
        h1, wth[3], wtl[3], nullptr, nullptr, nullptr, nullptr, h0, nullptr, N);
    agg_h16<64, true><<<gridN4, TB, 0, stream>>>(h0, csr, row_off, in_nrm, out_nrm, B4, h1, N);

    // L5: 64->64 agg-first. h0 = t5 = agg(g4) ; h1 = g5
    agg_h16<64, false><<<gridN4, TB, 0, stream>>>(h1, csr, row_off, nullptr, nullptr, nullptr, h0, N);
    gemm_h16<64, 64, true, false><<<MB, TB, 0, stream>>>(
        h0, wth[4], wtl[4], in_nrm, out_nrm, B5, nullptr, h1, nullptr, N);

    // L6: 64->64 agg-first. h0 = t6 = agg(g5) ; gemm+epilogue+W7-dot -> t7
    agg_h16<64, false><<<gridN4, TB, 0, stream>>>(h1, csr, row_off, nullptr, nullptr, nullptr, h0, N);
    gemm_h16<64, 64, true, true><<<MB, TB, 0, stream>>>(
        h0, wth[5], wtl[5], in_nrm, out_nrm, B6, W7, nullptr, t7, N);

    // out = agg(t7)*r + B7
    agg1_kernel<<<(N + 15) / 16, TB, 0, stream>>>(t7, csr, row_off, in_nrm, B7, out, N);
}